// Round 5
// baseline (552.259 us; speedup 1.0000x reference)
//
#include <hip/hip_runtime.h>

// Perona-Malik diffusion, 500 iters = 50 launches x 10 LDS-fused steps.
// Round-5: 4x4 register blocks with perimeter-only LDS exchange (top/bottom
// rows + packed side columns, all b128) -> ~3x fewer LDS-pipe cycles than the
// round-4 all-pixels-in-LDS scheme (LDS is one pipe/CU; it was the bottleneck).
// Update regrouped as nv = cc*c + cu*up + cd*dn + chl*lf + chr*rt with
// cc = 1-(cu+cd+chl+chr) precomputed: 5 VALU/px instead of 8.

#define HH 512
#define WW 512
#define NB 2
static constexpr float LAM   = 0.24f;
static constexpr float KCOND = 0.03f;
static constexpr float DEPS_ = 0.1f;
static constexpr int IMG      = HH * WW;
static constexpr int N_DEPTH  = NB * IMG;
static constexpr int CV_PER_B = (HH - 1) * WW;
static constexpr int CH_PER_B = HH * (WW - 1);
static constexpr int N_CV     = NB * CV_PER_B;
static constexpr int N_CH     = NB * CH_PER_B;

static constexpr int T_FUSE = 10, NSS = 50;       // 50 x 10 = 500
static constexpr int TILE_W = 64, TILE_H = 32;
static constexpr int HALO_X = 12, HALO_Y = 10;
static constexpr int RW = TILE_W + 2 * HALO_X;    // 88
static constexpr int RH = TILE_H + 2 * HALO_Y;    // 52
static constexpr int NQ_ROW = RW / 4;             // 22
static constexpr int NQUAD  = NQ_ROW * RH;        // (fallback use)
static constexpr int SSZ    = (RH + 2) * RW;      // fallback LDS

// coefficient planes (unchanged from round 4)
static constexpr int CVW = RW;                     // 88
static constexpr int CV_SZ = (RH + 1) * CVW;       // 4664
static constexpr int CHW = RW + 8;                 // 96
static constexpr int CH_SZ = RH * CHW;             // 4992
static constexpr int BLOB_BLK = CV_SZ + CH_SZ;

// register-block geometry
static constexpr int NBAND = RH / 4;               // 13 bands of 4 rows
static constexpr int NUNIT = NBAND * NQ_ROW;       // 286 units (4x4 px each)
static constexpr int NT2   = 320;                  // 5 waves
// LDS exchange layout (float indices), double-buffered:
static constexpr int RROW  = 92;                   // padded row stride
static constexpr int RT_O  = 0;                    // [NBAND+1][RROW] top rows (+ghost band NBAND)
static constexpr int RBS_O = RT_O + (NBAND + 1) * RROW;   // [NBAND+1][RROW] bottom-of-band-above (+ghost 0)
static constexpr int CL_O  = RBS_O + (NBAND + 1) * RROW;  // [NBAND][23][4] left cols (+ghost qc=22)
static constexpr int CRS_O = CL_O + NBAND * 23 * 4;       // [NBAND][23][4] right-col-of-left (+ghost 0)
static constexpr int BUF_SZ = CRS_O + NBAND * 23 * 4;     // 4968 floats (19.9 KB)

// fallback path (round-2 verified)
static constexpr int QPT_F = 5;

// ---- monotone float<->uint key for atomic min ----
__device__ __forceinline__ unsigned fkey(float f) {
    unsigned u = __float_as_uint(f);
    return (u & 0x80000000u) ? ~u : (u | 0x80000000u);
}
__device__ __forceinline__ float kinv(unsigned k) {
    return __uint_as_float((k & 0x80000000u) ? (k & 0x7fffffffu) : ~k);
}

__global__ void init_key_kernel(unsigned* key) { *key = 0xFFFFFFFFu; }

__global__ void min_kernel(const float* __restrict__ x, unsigned* key) {
    float m = 3.4e38f;
    for (int idx = blockIdx.x * blockDim.x + threadIdx.x; idx < N_DEPTH;
         idx += gridDim.x * blockDim.x)
        m = fminf(m, x[idx]);
    for (int off = 32; off > 0; off >>= 1) m = fminf(m, __shfl_down(m, off, 64));
    __shared__ float sm[4];
    int lane = threadIdx.x & 63, wv = threadIdx.x >> 6;
    if (lane == 0) sm[wv] = m;
    __syncthreads();
    if (threadIdx.x == 0) {
        float mm = fminf(fminf(sm[0], sm[1]), fminf(sm[2], sm[3]));
        atomicMin(key, fkey(mm));
    }
}

__global__ void coeff_kernel(const float* __restrict__ g, float* __restrict__ cv,
                             float* __restrict__ chh) {
    int idx = blockIdx.x * blockDim.x + threadIdx.x;
    constexpr float kk = KCOND * KCOND;
    if (idx < N_CV) {
        int b = idx / CV_PER_B;
        int r = idx - b * CV_PER_B;
        int i = r >> 9, j = r & (WW - 1);
        const float* gb = g + b * 3 * IMG + i * WW + j;
        float s = 0.f;
#pragma unroll
        for (int c = 0; c < 3; ++c) s += fabsf(gb[c * IMG + WW] - gb[c * IMG]);
        float m = s / 3.0f;
        cv[idx] = 1.0f / (1.0f + (m * m) / kk);
    } else if (idx < N_CV + N_CH) {
        int t = idx - N_CV;
        int b = t / CH_PER_B;
        int r = t - b * CH_PER_B;
        int i = r / (WW - 1);
        int j = r - i * (WW - 1);
        const float* gb = g + b * 3 * IMG + i * WW + j;
        float s = 0.f;
#pragma unroll
        for (int c = 0; c < 3; ++c) s += fabsf(gb[c * IMG + 1] - gb[c * IMG]);
        float m = s / 3.0f;
        chh[t] = 1.0f / (1.0f + (m * m) / kk);
    }
}

// One-time: bake predicated L*cv / L*ch into dense per-block planes.
__global__ __launch_bounds__(256) void prep_planes(const float* __restrict__ cv_g,
                                                   const float* __restrict__ ch_g,
                                                   float* __restrict__ blob) {
    const int blk = blockIdx.x;
    const int b   = blk >> 7, t = blk & 127;
    const int y0  = (t >> 3) * TILE_H;
    const int x0  = (t & 7) * TILE_W;
    const float* cvb = cv_g + b * CV_PER_B;
    const float* chb = ch_g + b * CH_PER_B;
    float* pv = blob + blk * BLOB_BLK;
    float* ph = pv + CV_SZ;
    for (int i = threadIdx.x; i < CV_SZ; i += 256) {
        int rr = i / CVW, x = i - rr * CVW;
        int gy = y0 - HALO_Y + rr, gx = x0 - HALO_X + x;
        bool ok = (rr >= 1) && (rr <= RH - 1) && (gy >= 1) && (gy <= HH - 1) &&
                  (gx >= 0) && (gx < WW);
        pv[i] = ok ? LAM * cvb[(gy - 1) * WW + gx] : 0.f;
    }
    for (int i = threadIdx.x; i < CH_SZ; i += 256) {
        int rr = i / CHW, xe = i - rr * CHW;
        int gy = y0 - HALO_Y + rr, gxe = x0 - HALO_X + xe;
        bool ok = (xe >= 1) && (xe <= RW - 1) && (gy >= 0) && (gy < HH) &&
                  (gxe >= 1) && (gxe < WW);
        ph[i] = ok ? LAM * chb[gy * (WW - 1) + (gxe - 1)] : 0.f;
    }
}

template <bool ADD_SHIFT, bool SUB_SHIFT>
__global__ __launch_bounds__(NT2, 1) void step_reg(
    const float* __restrict__ src, float* __restrict__ dst,
    const float* __restrict__ blob, const unsigned* __restrict__ key) {
    __shared__ float sb[2 * BUF_SZ];
    const int blk   = blockIdx.x;
    const int b_img = blk >> 7, t = blk & 127;
    const int y0 = (t >> 3) * TILE_H, x0 = (t & 7) * TILE_W;
    const float* srcb = src + b_img * IMG;
    const float* pv = blob + blk * BLOB_BLK;
    const float* ph = pv + CV_SZ;

    float shift = 0.f;
    if (ADD_SHIFT || SUB_SHIFT) shift = (kinv(*key) <= DEPS_) ? DEPS_ : 0.f;

    const int  tid = threadIdx.x;
    const bool act = tid < NUNIT;
    const int  u  = act ? tid : 0;
    const int  bb = u / NQ_ROW;          // band (0..12)
    const int  qc = u - bb * NQ_ROW;     // quad column (0..21)
    const int  x  = qc * 4;              // region col of block's left edge

    float v[4][4], vert[5][4], hz[4][5], cc[4][4];
    int   goffr[4];
    bool  rin[4];

    // LDS float-index offsets for this unit
    const int up_o = RBS_O + bb * RROW + x;          // read: bottom row of band above
    const int dn_o = RT_O + (bb + 1) * RROW + x;     // read: top row of band below
    const int lf_o = CRS_O + (bb * 23 + qc) * 4;     // read: right col of left unit
    const int rt_o = CL_O + (bb * 23 + qc + 1) * 4;  // read: left col of right unit
    const int wt_o = RT_O + bb * RROW + x;           // write: my top row
    const int wb_o = RBS_O + (bb + 1) * RROW + x;    // write: my bottom row
    const int wl_o = CL_O + (bb * 23 + qc) * 4;      // write: my left col
    const int wr_o = CRS_O + (bb * 23 + qc + 1) * 4; // write: my right col

    if (act) {
        // coefficients from planes (dense, aligned f4)
#pragma unroll
        for (int k = 0; k < 5; ++k) {
            float4 a = *reinterpret_cast<const float4*>(&pv[(4 * bb + k) * CVW + x]);
            vert[k][0] = a.x; vert[k][1] = a.y; vert[k][2] = a.z; vert[k][3] = a.w;
        }
#pragma unroll
        for (int k = 0; k < 4; ++k) {
            int r = 4 * bb + k;
            float4 h = *reinterpret_cast<const float4*>(&ph[r * CHW + x]);
            hz[k][0] = h.x; hz[k][1] = h.y; hz[k][2] = h.z; hz[k][3] = h.w;
            hz[k][4] = ph[r * CHW + x + 4];
        }
#pragma unroll
        for (int k = 0; k < 4; ++k)
#pragma unroll
            for (int j = 0; j < 4; ++j)
                cc[k][j] = 1.f - (vert[k][j] + vert[k + 1][j] + hz[k][j] + hz[k][j + 1]);

        // initial values
        int  gx    = x0 - HALO_X + x;
        bool gx_in = (gx >= 0) && (gx <= WW - 4);
#pragma unroll
        for (int k = 0; k < 4; ++k) {
            int r  = 4 * bb + k;
            int gy = y0 - HALO_Y + r;
            rin[k]   = gx_in && (gy >= 0) && (gy < HH);
            goffr[k] = rin[k] ? (gy * WW + gx) : 0;
            float4 tv = {0.f, 0.f, 0.f, 0.f};
            if (rin[k]) tv = *reinterpret_cast<const float4*>(srcb + goffr[k]);
            if (ADD_SHIFT && rin[k]) {
                tv.x += shift; tv.y += shift; tv.z += shift; tv.w += shift;
            }
            v[k][0] = tv.x; v[k][1] = tv.y; v[k][2] = tv.z; v[k][3] = tv.w;
        }
    }

    // zero ghost slots (both buffers) — never written during iterations
    for (int i = tid; i < RROW; i += NT2) {
        sb[RT_O + NBAND * RROW + i] = 0.f;
        sb[RBS_O + i] = 0.f;
        sb[BUF_SZ + RT_O + NBAND * RROW + i] = 0.f;
        sb[BUF_SZ + RBS_O + i] = 0.f;
    }
    for (int i = tid; i < NBAND; i += NT2) {
#pragma unroll
        for (int j = 0; j < 4; ++j) {
            sb[CL_O + (i * 23 + 22) * 4 + j] = 0.f;
            sb[CRS_O + (i * 23) * 4 + j] = 0.f;
            sb[BUF_SZ + CL_O + (i * 23 + 22) * 4 + j] = 0.f;
            sb[BUF_SZ + CRS_O + (i * 23) * 4 + j] = 0.f;
        }
    }
    // publish initial perimeter into buffer 0
    if (act) {
        *reinterpret_cast<float4*>(&sb[wt_o]) = float4{v[0][0], v[0][1], v[0][2], v[0][3]};
        *reinterpret_cast<float4*>(&sb[wb_o]) = float4{v[3][0], v[3][1], v[3][2], v[3][3]};
        *reinterpret_cast<float4*>(&sb[wl_o]) = float4{v[0][0], v[1][0], v[2][0], v[3][0]};
        *reinterpret_cast<float4*>(&sb[wr_o]) = float4{v[0][3], v[1][3], v[2][3], v[3][3]};
    }
    __syncthreads();

    int cur = 0;
    for (int it = 0; it < T_FUSE; ++it) {
        int nxt = cur ^ 1;
        if (act) {
            const float* bc = &sb[cur * BUF_SZ];
            float*       bn = &sb[nxt * BUF_SZ];
            float4 up  = *reinterpret_cast<const float4*>(&bc[up_o]);
            float4 dn  = *reinterpret_cast<const float4*>(&bc[dn_o]);
            float4 lf  = *reinterpret_cast<const float4*>(&bc[lf_o]);
            float4 rt4 = *reinterpret_cast<const float4*>(&bc[rt_o]);
            float upv[4] = {up.x, up.y, up.z, up.w};
            float dnv[4] = {dn.x, dn.y, dn.z, dn.w};
            float lfv[4] = {lf.x, lf.y, lf.z, lf.w};
            float rtv[4] = {rt4.x, rt4.y, rt4.z, rt4.w};
            float nv[4][4];
#pragma unroll
            for (int k = 0; k < 4; ++k) {
#pragma unroll
                for (int j = 0; j < 4; ++j) {
                    float un = (k == 0) ? upv[j] : v[k - 1][j];
                    float dd = (k == 3) ? dnv[j] : v[k + 1][j];
                    float ll = (j == 0) ? lfv[k] : v[k][j - 1];
                    float rr = (j == 3) ? rtv[k] : v[k][j + 1];
                    nv[k][j] = cc[k][j] * v[k][j] + vert[k][j] * un +
                               vert[k + 1][j] * dd + hz[k][j] * ll + hz[k][j + 1] * rr;
                }
            }
            *reinterpret_cast<float4*>(&bn[wt_o]) = float4{nv[0][0], nv[0][1], nv[0][2], nv[0][3]};
            *reinterpret_cast<float4*>(&bn[wb_o]) = float4{nv[3][0], nv[3][1], nv[3][2], nv[3][3]};
            *reinterpret_cast<float4*>(&bn[wl_o]) = float4{nv[0][0], nv[1][0], nv[2][0], nv[3][0]};
            *reinterpret_cast<float4*>(&bn[wr_o]) = float4{nv[0][3], nv[1][3], nv[2][3], nv[3][3]};
#pragma unroll
            for (int k = 0; k < 4; ++k)
#pragma unroll
                for (int j = 0; j < 4; ++j) v[k][j] = nv[k][j];
        }
        cur = nxt;
        __syncthreads();
    }

    // store interior (exact after T_FUSE steps)
    float* dstb = dst + b_img * IMG;
    if (act && x >= HALO_X && x < HALO_X + TILE_W) {
#pragma unroll
        for (int k = 0; k < 4; ++k) {
            int r = 4 * bb + k;
            if (r >= HALO_Y && r < HALO_Y + TILE_H) {
                float4 o{v[k][0], v[k][1], v[k][2], v[k][3]};
                if (SUB_SHIFT) { o.x -= shift; o.y -= shift; o.z -= shift; o.w -= shift; }
                *reinterpret_cast<float4*>(dstb + goffr[k]) = o;
            }
        }
    }
}

// -------- fallback (round-2 verified, inline gather, 256 threads) --------
template <bool ADD_SHIFT, bool SUB_SHIFT>
__global__ __launch_bounds__(256, 1) void step_fused(
    const float* __restrict__ src, float* __restrict__ dst,
    const float* __restrict__ cv_g, const float* __restrict__ ch_g,
    const unsigned* __restrict__ key) {
    __shared__ float sb[2][SSZ];
    const int blk = blockIdx.x;
    const int b = blk >> 7, t = blk & 127;
    const int y0 = (t >> 3) * TILE_H, x0 = (t & 7) * TILE_W;
    const float* cvb = cv_g + b * CV_PER_B;
    const float* chb = ch_g + b * CH_PER_B;
    const float* srcb = src + b * IMG;
    float* dstb = dst + b * IMG;
    float shift = 0.f;
    if (ADD_SHIFT || SUB_SHIFT) shift = (kinv(*key) <= DEPS_) ? DEPS_ : 0.f;
    const int tid = threadIdx.x;
    float v[QPT_F][4], cu[QPT_F][4], cd[QPT_F][4], chq[QPT_F][5];
    int roff[QPT_F], rr[QPT_F], xx[QPT_F];
    bool act[QPT_F];
#pragma unroll
    for (int q = 0; q < QPT_F; ++q) {
        int qi = tid + q * 256;
        act[q] = qi < NQUAD;
        int qc = act[q] ? qi : 0;
        int r = qc / NQ_ROW;
        int x = (qc - r * NQ_ROW) * 4;
        rr[q] = r; xx[q] = x;
        roff[q] = (r + 1) * RW + x;
        int gy = y0 - HALO_Y + r, gx = x0 - HALO_X + x;
        bool gy_in = (gy >= 0) && (gy < HH);
#pragma unroll
        for (int j = 0; j < 4; ++j) {
            int gxx = gx + j;
            bool gx_in = (gxx >= 0) && (gxx < WW);
            bool vin = act[q] && gy_in && gx_in;
            float val = vin ? srcb[gy * WW + gxx] : 0.f;
            if (ADD_SHIFT) val += shift;
            v[q][j] = vin ? val : 0.f;
            bool up_ok = act[q] && (r >= 1) && (gy >= 1) && (gy < HH) && gx_in;
            cu[q][j] = up_ok ? LAM * cvb[(gy - 1) * WW + gxx] : 0.f;
            bool dn_ok = act[q] && (r <= RH - 2) && (gy >= 0) && (gy < HH - 1) && gx_in;
            cd[q][j] = dn_ok ? LAM * cvb[gy * WW + gxx] : 0.f;
        }
#pragma unroll
        for (int jj = 0; jj < 5; ++jj) {
            int xe = x + jj, gxe = gx + jj;
            bool ok = act[q] && (xe >= 1) && (xe <= RW - 1) && gy_in &&
                      (gxe >= 1) && (gxe < WW);
            chq[q][jj] = ok ? LAM * chb[gy * (WW - 1) + (gxe - 1)] : 0.f;
        }
    }
    for (int i = tid; i < RW; i += 256) {
        sb[0][i] = 0.f; sb[0][(RH + 1) * RW + i] = 0.f;
        sb[1][i] = 0.f; sb[1][(RH + 1) * RW + i] = 0.f;
    }
#pragma unroll
    for (int q = 0; q < QPT_F; ++q)
        if (act[q])
            *reinterpret_cast<float4*>(&sb[0][roff[q]]) =
                float4{v[q][0], v[q][1], v[q][2], v[q][3]};
    __syncthreads();
    int cur = 0;
    for (int it = 0; it < T_FUSE; ++it) {
        float nv[QPT_F][4];
#pragma unroll
        for (int q = 0; q < QPT_F; ++q) {
            const float* s = sb[cur];
            float4 up = *reinterpret_cast<const float4*>(&s[roff[q] - RW]);
            float4 dn = *reinterpret_cast<const float4*>(&s[roff[q] + RW]);
            float lf = s[roff[q] - 1];
            float rt = s[roff[q] + 4];
            float c0 = v[q][0], c1 = v[q][1], c2 = v[q][2], c3 = v[q][3];
            nv[q][0] = c0 - cu[q][0] * (c0 - up.x) + cd[q][0] * (dn.x - c0)
                          - chq[q][0] * (c0 - lf) + chq[q][1] * (c1 - c0);
            nv[q][1] = c1 - cu[q][1] * (c1 - up.y) + cd[q][1] * (dn.y - c1)
                          - chq[q][1] * (c1 - c0) + chq[q][2] * (c2 - c1);
            nv[q][2] = c2 - cu[q][2] * (c2 - up.z) + cd[q][2] * (dn.z - c2)
                          - chq[q][2] * (c2 - c1) + chq[q][3] * (c3 - c2);
            nv[q][3] = c3 - cu[q][3] * (c3 - up.w) + cd[q][3] * (dn.w - c3)
                          - chq[q][3] * (c3 - c2) + chq[q][4] * (rt - c3);
        }
        int nxt = cur ^ 1;
#pragma unroll
        for (int q = 0; q < QPT_F; ++q) {
            if (act[q])
                *reinterpret_cast<float4*>(&sb[nxt][roff[q]]) =
                    float4{nv[q][0], nv[q][1], nv[q][2], nv[q][3]};
            v[q][0] = nv[q][0]; v[q][1] = nv[q][1];
            v[q][2] = nv[q][2]; v[q][3] = nv[q][3];
        }
        cur = nxt;
        __syncthreads();
    }
#pragma unroll
    for (int q = 0; q < QPT_F; ++q) {
        if (!act[q]) continue;
        int r = rr[q], x = xx[q];
        if (r >= HALO_Y && r < HALO_Y + TILE_H && x >= HALO_X && x < HALO_X + TILE_W) {
            int gy = y0 - HALO_Y + r, gx = x0 - HALO_X + x;
            float4 o{v[q][0], v[q][1], v[q][2], v[q][3]};
            if (SUB_SHIFT) { o.x -= shift; o.y -= shift; o.z -= shift; o.w -= shift; }
            *reinterpret_cast<float4*>(dstb + gy * WW + gx) = o;
        }
    }
}

extern "C" void kernel_launch(void* const* d_in, const int* in_sizes, int n_in,
                              void* d_out, int out_size, void* d_ws, size_t ws_size,
                              hipStream_t stream) {
    const float* guide   = (const float*)d_in[0];
    const float* initial = (const float*)d_in[1];
    float* out    = (float*)d_out;
    float* out_y  = out;
    float* out_cv = out + N_DEPTH;
    float* out_ch = out + N_DEPTH + N_CV;

    unsigned* key = (unsigned*)d_ws;
    float* wsf    = (float*)d_ws;
    float* bufA   = wsf + 64;
    float* bufB   = bufA + N_DEPTH;
    float* blob   = bufB + N_DEPTH;

    const size_t need = (size_t)(64 + 2 * N_DEPTH + 256 * BLOB_BLK) * 4;
    const bool fast = ws_size >= need;

    hipLaunchKernelGGL(init_key_kernel, dim3(1), dim3(1), 0, stream, key);
    hipLaunchKernelGGL(min_kernel, dim3(256), dim3(256), 0, stream, initial, key);

    int nco = N_CV + N_CH;
    hipLaunchKernelGGL(coeff_kernel, dim3((nco + 255) / 256), dim3(256), 0, stream,
                       guide, out_cv, out_ch);
    if (fast)
        hipLaunchKernelGGL(prep_planes, dim3(256), dim3(256), 0, stream,
                           out_cv, out_ch, blob);

    float* bufs[2] = {bufA, bufB};
    for (int k = 0; k < NSS; ++k) {
        const float* src = (k == 0) ? initial : bufs[(k + 1) & 1];
        float*       dst = (k == NSS - 1) ? out_y : bufs[k & 1];
        if (fast) {
            if (k == 0)
                hipLaunchKernelGGL((step_reg<true, false>), dim3(256), dim3(NT2), 0,
                                   stream, src, dst, blob, key);
            else if (k == NSS - 1)
                hipLaunchKernelGGL((step_reg<false, true>), dim3(256), dim3(NT2), 0,
                                   stream, src, dst, blob, key);
            else
                hipLaunchKernelGGL((step_reg<false, false>), dim3(256), dim3(NT2), 0,
                                   stream, src, dst, blob, key);
        } else {
            if (k == 0)
                hipLaunchKernelGGL((step_fused<true, false>), dim3(256), dim3(256), 0,
                                   stream, src, dst, out_cv, out_ch, key);
            else if (k == NSS - 1)
                hipLaunchKernelGGL((step_fused<false, true>), dim3(256), dim3(256), 0,
                                   stream, src, dst, out_cv, out_ch, key);
            else
                hipLaunchKernelGGL((step_fused<false, false>), dim3(256), dim3(256), 0,
                                   stream, src, dst, out_cv, out_ch, key);
        }
    }
}

// Round 6
// 525.318 us; speedup vs baseline: 1.0513x; 1.0513x over previous
//
#include <hip/hip_runtime.h>

// Perona-Malik diffusion, 500 iters = 25 launches x 20 LDS-fused steps.
// Round-6: (a) T_FUSE 10->20 — inner loop is barrier/latency-bound (round-5
// evidence: 2.5x fewer LDS ops changed nothing), so amortize the ~5-6 us
// fixed per-launch cost over 2x more iterations; (b) coefficients come from
// GLOBAL zero-padded planes (5 MB, stride 560) instead of 16 MB per-block
// blobs — region-edge coeff zeroing is unnecessary (halo garbage propagates
// 1 px/iter < 20-px halo), only image-border zeros matter.
// Per-thread 4x4 px register block, perimeter-only b128 LDS exchange.

#define HH 512
#define WW 512
#define NB 2
static constexpr float LAM   = 0.24f;
static constexpr float KCOND = 0.03f;
static constexpr float DEPS_ = 0.1f;
static constexpr int IMG      = HH * WW;
static constexpr int N_DEPTH  = NB * IMG;
static constexpr int CV_PER_B = (HH - 1) * WW;
static constexpr int CH_PER_B = HH * (WW - 1);
static constexpr int N_CV     = NB * CV_PER_B;
static constexpr int N_CH     = NB * CH_PER_B;

// ---- fast path geometry (T=20) ----
static constexpr int T_FUSE = 20, NSS = 25;        // 25 x 20 = 500
static constexpr int TILE_W = 64, TILE_H = 32;
static constexpr int HALO   = 20;
static constexpr int RW = TILE_W + 2 * HALO;       // 104
static constexpr int RH = TILE_H + 2 * HALO;       // 72
static constexpr int NQ_ROW = RW / 4;              // 26
static constexpr int NBAND  = RH / 4;              // 18
static constexpr int NUNIT  = NBAND * NQ_ROW;      // 468
static constexpr int NT     = 512;
// LDS exchange (floats), double-buffered
static constexpr int RROW  = RW + 4;               // 108
static constexpr int RT_O  = 0;                                  // [NBAND+1][RROW]
static constexpr int RBS_O = RT_O + (NBAND + 1) * RROW;          // [NBAND+1][RROW]
static constexpr int CL_O  = RBS_O + (NBAND + 1) * RROW;         // [NBAND][27][4]
static constexpr int CRS_O = CL_O + NBAND * (NQ_ROW + 1) * 4;    // [NBAND][27][4]
static constexpr int BUF_SZ = CRS_O + NBAND * (NQ_ROW + 1) * 4;  // 7992 (32 KB)

// global padded coefficient planes
static constexpr int PAD  = 24;                    // >= HALO, multiple of 4
static constexpr int PSTR = WW + 2 * PAD;          // 560
static constexpr int PV_SZ = (HH + 2 * PAD + 1) * PSTR;  // 561*560
static constexpr int PH_SZ = (HH + 2 * PAD) * PSTR;      // 560*560
static constexpr int PLANE_IMG = PV_SZ + PH_SZ;

// ---- fallback geometry (round-2 verified, T=10, inline gather) ----
static constexpr int T_FUSE_F = 10, NSS_F = 50;
static constexpr int HALO_XF = 12, HALO_YF = 10;
static constexpr int RW_F = TILE_W + 2 * HALO_XF;  // 88
static constexpr int RH_F = TILE_H + 2 * HALO_YF;  // 52
static constexpr int NQ_ROW_F = RW_F / 4;          // 22
static constexpr int NQUAD_F  = NQ_ROW_F * RH_F;
static constexpr int QPT_F    = 5;
static constexpr int SSZ_F    = (RH_F + 2) * RW_F;

// ---- monotone float<->uint key for atomic min ----
__device__ __forceinline__ unsigned fkey(float f) {
    unsigned u = __float_as_uint(f);
    return (u & 0x80000000u) ? ~u : (u | 0x80000000u);
}
__device__ __forceinline__ float kinv(unsigned k) {
    return __uint_as_float((k & 0x80000000u) ? (k & 0x7fffffffu) : ~k);
}

__global__ void init_key_kernel(unsigned* key) { *key = 0xFFFFFFFFu; }

__global__ void min_kernel(const float* __restrict__ x, unsigned* key) {
    float m = 3.4e38f;
    for (int idx = blockIdx.x * blockDim.x + threadIdx.x; idx < N_DEPTH;
         idx += gridDim.x * blockDim.x)
        m = fminf(m, x[idx]);
    for (int off = 32; off > 0; off >>= 1) m = fminf(m, __shfl_down(m, off, 64));
    __shared__ float sm[4];
    int lane = threadIdx.x & 63, wv = threadIdx.x >> 6;
    if (lane == 0) sm[wv] = m;
    __syncthreads();
    if (threadIdx.x == 0) {
        float mm = fminf(fminf(sm[0], sm[1]), fminf(sm[2], sm[3]));
        atomicMin(key, fkey(mm));
    }
}

__global__ void coeff_kernel(const float* __restrict__ g, float* __restrict__ cv,
                             float* __restrict__ chh) {
    int idx = blockIdx.x * blockDim.x + threadIdx.x;
    constexpr float kk = KCOND * KCOND;
    if (idx < N_CV) {
        int b = idx / CV_PER_B;
        int r = idx - b * CV_PER_B;
        int i = r >> 9, j = r & (WW - 1);
        const float* gb = g + b * 3 * IMG + i * WW + j;
        float s = 0.f;
#pragma unroll
        for (int c = 0; c < 3; ++c) s += fabsf(gb[c * IMG + WW] - gb[c * IMG]);
        float m = s / 3.0f;
        cv[idx] = 1.0f / (1.0f + (m * m) / kk);
    } else if (idx < N_CV + N_CH) {
        int t = idx - N_CV;
        int b = t / CH_PER_B;
        int r = t - b * CH_PER_B;
        int i = r / (WW - 1);
        int j = r - i * (WW - 1);
        const float* gb = g + b * 3 * IMG + i * WW + j;
        float s = 0.f;
#pragma unroll
        for (int c = 0; c < 3; ++c) s += fabsf(gb[c * IMG + 1] - gb[c * IMG]);
        float m = s / 3.0f;
        chh[t] = 1.0f / (1.0f + (m * m) / kk);
    }
}

// One-time: global zero-padded L*cv / L*ch planes, stride PSTR.
// PV[(gy+PAD)*PSTR + gx+PAD] = L*cv of edge ABOVE image row gy (0 unless
//   1<=gy<=HH-1, 0<=gx<WW). PH[...] = L*ch of edge whose RIGHT px is gxe
//   (0 unless 0<=gy<HH, 1<=gxe<WW).
__global__ void prep_planes(const float* __restrict__ cv_g,
                            const float* __restrict__ ch_g,
                            float* __restrict__ planes) {
    int idx = blockIdx.x * blockDim.x + threadIdx.x;
    int total = NB * PLANE_IMG;
    if (idx >= total) return;
    int b = idx / PLANE_IMG;
    int r = idx - b * PLANE_IMG;
    float* dst = planes + b * PLANE_IMG;
    if (r < PV_SZ) {
        int row = r / PSTR, col = r - row * PSTR;
        int gy = row - PAD, gx = col - PAD;
        bool ok = (gy >= 1) && (gy <= HH - 1) && (gx >= 0) && (gx < WW);
        dst[r] = ok ? LAM * cv_g[b * CV_PER_B + (gy - 1) * WW + gx] : 0.f;
    } else {
        int rr = r - PV_SZ;
        int row = rr / PSTR, col = rr - row * PSTR;
        int gy = row - PAD, gxe = col - PAD;
        bool ok = (gy >= 0) && (gy < HH) && (gxe >= 1) && (gxe < WW);
        dst[r] = ok ? LAM * ch_g[b * CH_PER_B + gy * (WW - 1) + (gxe - 1)] : 0.f;
    }
}

template <bool ADD_SHIFT, bool SUB_SHIFT>
__global__ __launch_bounds__(NT) void step_t20(
    const float* __restrict__ src, float* __restrict__ dst,
    const float* __restrict__ planes, const unsigned* __restrict__ key) {
    __shared__ float sb[2 * BUF_SZ];
    const int blk   = blockIdx.x;
    const int b_img = blk >> 7, t = blk & 127;
    const int y0 = (t >> 3) * TILE_H, x0 = (t & 7) * TILE_W;
    const float* srcb = src + b_img * IMG;
    const float* PVb  = planes + b_img * PLANE_IMG;
    const float* PHb  = PVb + PV_SZ;

    float shift = 0.f;
    if (ADD_SHIFT || SUB_SHIFT) shift = (kinv(*key) <= DEPS_) ? DEPS_ : 0.f;

    const int  tid = threadIdx.x;
    const bool act = tid < NUNIT;
    const int  u   = act ? tid : 0;
    const int  bb  = u / NQ_ROW;
    const int  qc  = u - bb * NQ_ROW;
    const int  x   = qc * 4;
    const int  gx  = x0 - HALO + x;        // multiple of 4
    const int  gyb = y0 - HALO + 4 * bb;

    const int up_o = RBS_O + bb * RROW + x;
    const int dn_o = RT_O + (bb + 1) * RROW + x;
    const int lf_o = CRS_O + (bb * (NQ_ROW + 1) + qc) * 4;
    const int rt_o = CL_O + (bb * (NQ_ROW + 1) + qc + 1) * 4;
    const int wt_o = RT_O + bb * RROW + x;
    const int wb_o = RBS_O + (bb + 1) * RROW + x;
    const int wl_o = CL_O + (bb * (NQ_ROW + 1) + qc) * 4;
    const int wr_o = CRS_O + (bb * (NQ_ROW + 1) + qc + 1) * 4;

    float v[4][4], vert[5][4], hz[4][5], cc[4][4];
    int   goffr[4];
    bool  rin[4];

    if (act) {
        const int pbase = (gyb + PAD) * PSTR + (gx + PAD);
#pragma unroll
        for (int k = 0; k < 5; ++k) {
            float4 a = *reinterpret_cast<const float4*>(&PVb[pbase + k * PSTR]);
            vert[k][0] = a.x; vert[k][1] = a.y; vert[k][2] = a.z; vert[k][3] = a.w;
        }
#pragma unroll
        for (int k = 0; k < 4; ++k) {
            float4 h = *reinterpret_cast<const float4*>(&PHb[pbase + k * PSTR]);
            hz[k][0] = h.x; hz[k][1] = h.y; hz[k][2] = h.z; hz[k][3] = h.w;
            hz[k][4] = PHb[pbase + k * PSTR + 4];
        }
#pragma unroll
        for (int k = 0; k < 4; ++k)
#pragma unroll
            for (int j = 0; j < 4; ++j)
                cc[k][j] = 1.f - (vert[k][j] + vert[k + 1][j] + hz[k][j] + hz[k][j + 1]);

        bool gx_in = (gx >= 0) && (gx < WW);
#pragma unroll
        for (int k = 0; k < 4; ++k) {
            int gy  = gyb + k;
            rin[k]   = gx_in && (gy >= 0) && (gy < HH);
            goffr[k] = rin[k] ? (gy * WW + gx) : 0;
            float4 tv = {0.f, 0.f, 0.f, 0.f};
            if (rin[k]) tv = *reinterpret_cast<const float4*>(srcb + goffr[k]);
            if (ADD_SHIFT && rin[k]) {
                tv.x += shift; tv.y += shift; tv.z += shift; tv.w += shift;
            }
            v[k][0] = tv.x; v[k][1] = tv.y; v[k][2] = tv.z; v[k][3] = tv.w;
        }
    }

    // zero ghost slots (both buffers); never written during iterations
    for (int i = tid; i < RROW; i += NT) {
        sb[RT_O + NBAND * RROW + i] = 0.f;
        sb[RBS_O + i] = 0.f;
        sb[BUF_SZ + RT_O + NBAND * RROW + i] = 0.f;
        sb[BUF_SZ + RBS_O + i] = 0.f;
    }
    for (int i = tid; i < NBAND; i += NT) {
#pragma unroll
        for (int j = 0; j < 4; ++j) {
            sb[CL_O + (i * (NQ_ROW + 1) + NQ_ROW) * 4 + j] = 0.f;
            sb[CRS_O + (i * (NQ_ROW + 1)) * 4 + j] = 0.f;
            sb[BUF_SZ + CL_O + (i * (NQ_ROW + 1) + NQ_ROW) * 4 + j] = 0.f;
            sb[BUF_SZ + CRS_O + (i * (NQ_ROW + 1)) * 4 + j] = 0.f;
        }
    }
    if (act) {
        *reinterpret_cast<float4*>(&sb[wt_o]) = float4{v[0][0], v[0][1], v[0][2], v[0][3]};
        *reinterpret_cast<float4*>(&sb[wb_o]) = float4{v[3][0], v[3][1], v[3][2], v[3][3]};
        *reinterpret_cast<float4*>(&sb[wl_o]) = float4{v[0][0], v[1][0], v[2][0], v[3][0]};
        *reinterpret_cast<float4*>(&sb[wr_o]) = float4{v[0][3], v[1][3], v[2][3], v[3][3]};
    }
    __syncthreads();

    int cur = 0;
    for (int it = 0; it < T_FUSE; ++it) {
        int nxt = cur ^ 1;
        if (act) {
            const float* bc = &sb[cur * BUF_SZ];
            float*       bn = &sb[nxt * BUF_SZ];
            float4 up  = *reinterpret_cast<const float4*>(&bc[up_o]);
            float4 dn  = *reinterpret_cast<const float4*>(&bc[dn_o]);
            float4 lf  = *reinterpret_cast<const float4*>(&bc[lf_o]);
            float4 rt4 = *reinterpret_cast<const float4*>(&bc[rt_o]);
            float upv[4] = {up.x, up.y, up.z, up.w};
            float dnv[4] = {dn.x, dn.y, dn.z, dn.w};
            float lfv[4] = {lf.x, lf.y, lf.z, lf.w};
            float rtv[4] = {rt4.x, rt4.y, rt4.z, rt4.w};
            float nv[4][4];
#pragma unroll
            for (int k = 0; k < 4; ++k) {
#pragma unroll
                for (int j = 0; j < 4; ++j) {
                    float un = (k == 0) ? upv[j] : v[k - 1][j];
                    float dd = (k == 3) ? dnv[j] : v[k + 1][j];
                    float ll = (j == 0) ? lfv[k] : v[k][j - 1];
                    float rr = (j == 3) ? rtv[k] : v[k][j + 1];
                    nv[k][j] = cc[k][j] * v[k][j] + vert[k][j] * un +
                               vert[k + 1][j] * dd + hz[k][j] * ll + hz[k][j + 1] * rr;
                }
            }
            *reinterpret_cast<float4*>(&bn[wt_o]) = float4{nv[0][0], nv[0][1], nv[0][2], nv[0][3]};
            *reinterpret_cast<float4*>(&bn[wb_o]) = float4{nv[3][0], nv[3][1], nv[3][2], nv[3][3]};
            *reinterpret_cast<float4*>(&bn[wl_o]) = float4{nv[0][0], nv[1][0], nv[2][0], nv[3][0]};
            *reinterpret_cast<float4*>(&bn[wr_o]) = float4{nv[0][3], nv[1][3], nv[2][3], nv[3][3]};
#pragma unroll
            for (int k = 0; k < 4; ++k)
#pragma unroll
                for (int j = 0; j < 4; ++j) v[k][j] = nv[k][j];
        }
        cur = nxt;
        __syncthreads();
    }

    // store interior (exact after T_FUSE steps: halo 20 >= T)
    float* dstb = dst + b_img * IMG;
    if (act && qc >= HALO / 4 && qc < (HALO + TILE_W) / 4 &&
        bb >= HALO / 4 && bb < (HALO + TILE_H) / 4) {
#pragma unroll
        for (int k = 0; k < 4; ++k) {
            float4 o{v[k][0], v[k][1], v[k][2], v[k][3]};
            if (SUB_SHIFT) { o.x -= shift; o.y -= shift; o.z -= shift; o.w -= shift; }
            *reinterpret_cast<float4*>(dstb + goffr[k]) = o;
        }
    }
}

// -------- fallback (round-2 verified, inline gather, 256 threads) --------
template <bool ADD_SHIFT, bool SUB_SHIFT>
__global__ __launch_bounds__(256, 1) void step_fused(
    const float* __restrict__ src, float* __restrict__ dst,
    const float* __restrict__ cv_g, const float* __restrict__ ch_g,
    const unsigned* __restrict__ key) {
    __shared__ float sb[2][SSZ_F];
    const int blk = blockIdx.x;
    const int b = blk >> 7, t = blk & 127;
    const int y0 = (t >> 3) * TILE_H, x0 = (t & 7) * TILE_W;
    const float* cvb = cv_g + b * CV_PER_B;
    const float* chb = ch_g + b * CH_PER_B;
    const float* srcb = src + b * IMG;
    float* dstb = dst + b * IMG;
    float shift = 0.f;
    if (ADD_SHIFT || SUB_SHIFT) shift = (kinv(*key) <= DEPS_) ? DEPS_ : 0.f;
    const int tid = threadIdx.x;
    float v[QPT_F][4], cu[QPT_F][4], cd[QPT_F][4], chq[QPT_F][5];
    int roff[QPT_F], rr[QPT_F], xx[QPT_F];
    bool act[QPT_F];
#pragma unroll
    for (int q = 0; q < QPT_F; ++q) {
        int qi = tid + q * 256;
        act[q] = qi < NQUAD_F;
        int qc = act[q] ? qi : 0;
        int r = qc / NQ_ROW_F;
        int x = (qc - r * NQ_ROW_F) * 4;
        rr[q] = r; xx[q] = x;
        roff[q] = (r + 1) * RW_F + x;
        int gy = y0 - HALO_YF + r, gx = x0 - HALO_XF + x;
        bool gy_in = (gy >= 0) && (gy < HH);
#pragma unroll
        for (int j = 0; j < 4; ++j) {
            int gxx = gx + j;
            bool gx_in = (gxx >= 0) && (gxx < WW);
            bool vin = act[q] && gy_in && gx_in;
            float val = vin ? srcb[gy * WW + gxx] : 0.f;
            if (ADD_SHIFT) val += shift;
            v[q][j] = vin ? val : 0.f;
            bool up_ok = act[q] && (r >= 1) && (gy >= 1) && (gy < HH) && gx_in;
            cu[q][j] = up_ok ? LAM * cvb[(gy - 1) * WW + gxx] : 0.f;
            bool dn_ok = act[q] && (r <= RH_F - 2) && (gy >= 0) && (gy < HH - 1) && gx_in;
            cd[q][j] = dn_ok ? LAM * cvb[gy * WW + gxx] : 0.f;
        }
#pragma unroll
        for (int jj = 0; jj < 5; ++jj) {
            int xe = x + jj, gxe = gx + jj;
            bool ok = act[q] && (xe >= 1) && (xe <= RW_F - 1) && gy_in &&
                      (gxe >= 1) && (gxe < WW);
            chq[q][jj] = ok ? LAM * chb[gy * (WW - 1) + (gxe - 1)] : 0.f;
        }
    }
    for (int i = tid; i < RW_F; i += 256) {
        sb[0][i] = 0.f; sb[0][(RH_F + 1) * RW_F + i] = 0.f;
        sb[1][i] = 0.f; sb[1][(RH_F + 1) * RW_F + i] = 0.f;
    }
#pragma unroll
    for (int q = 0; q < QPT_F; ++q)
        if (act[q])
            *reinterpret_cast<float4*>(&sb[0][roff[q]]) =
                float4{v[q][0], v[q][1], v[q][2], v[q][3]};
    __syncthreads();
    int cur = 0;
    for (int it = 0; it < T_FUSE_F; ++it) {
        float nv[QPT_F][4];
#pragma unroll
        for (int q = 0; q < QPT_F; ++q) {
            const float* s = sb[cur];
            float4 up = *reinterpret_cast<const float4*>(&s[roff[q] - RW_F]);
            float4 dn = *reinterpret_cast<const float4*>(&s[roff[q] + RW_F]);
            float lf = s[roff[q] - 1];
            float rt = s[roff[q] + 4];
            float c0 = v[q][0], c1 = v[q][1], c2 = v[q][2], c3 = v[q][3];
            nv[q][0] = c0 - cu[q][0] * (c0 - up.x) + cd[q][0] * (dn.x - c0)
                          - chq[q][0] * (c0 - lf) + chq[q][1] * (c1 - c0);
            nv[q][1] = c1 - cu[q][1] * (c1 - up.y) + cd[q][1] * (dn.y - c1)
                          - chq[q][1] * (c1 - c0) + chq[q][2] * (c2 - c1);
            nv[q][2] = c2 - cu[q][2] * (c2 - up.z) + cd[q][2] * (dn.z - c2)
                          - chq[q][2] * (c2 - c1) + chq[q][3] * (c3 - c2);
            nv[q][3] = c3 - cu[q][3] * (c3 - up.w) + cd[q][3] * (dn.w - c3)
                          - chq[q][3] * (c3 - c2) + chq[q][4] * (rt - c3);
        }
        int nxt = cur ^ 1;
#pragma unroll
        for (int q = 0; q < QPT_F; ++q) {
            if (act[q])
                *reinterpret_cast<float4*>(&sb[nxt][roff[q]]) =
                    float4{nv[q][0], nv[q][1], nv[q][2], nv[q][3]};
            v[q][0] = nv[q][0]; v[q][1] = nv[q][1];
            v[q][2] = nv[q][2]; v[q][3] = nv[q][3];
        }
        cur = nxt;
        __syncthreads();
    }
#pragma unroll
    for (int q = 0; q < QPT_F; ++q) {
        if (!act[q]) continue;
        int r = rr[q], x = xx[q];
        if (r >= HALO_YF && r < HALO_YF + TILE_H && x >= HALO_XF && x < HALO_XF + TILE_W) {
            int gy = y0 - HALO_YF + r, gx = x0 - HALO_XF + x;
            float4 o{v[q][0], v[q][1], v[q][2], v[q][3]};
            if (SUB_SHIFT) { o.x -= shift; o.y -= shift; o.z -= shift; o.w -= shift; }
            *reinterpret_cast<float4*>(dstb + gy * WW + gx) = o;
        }
    }
}

extern "C" void kernel_launch(void* const* d_in, const int* in_sizes, int n_in,
                              void* d_out, int out_size, void* d_ws, size_t ws_size,
                              hipStream_t stream) {
    const float* guide   = (const float*)d_in[0];
    const float* initial = (const float*)d_in[1];
    float* out    = (float*)d_out;
    float* out_y  = out;
    float* out_cv = out + N_DEPTH;
    float* out_ch = out + N_DEPTH + N_CV;

    unsigned* key = (unsigned*)d_ws;
    float* wsf    = (float*)d_ws;
    float* bufA   = wsf + 64;
    float* bufB   = bufA + N_DEPTH;
    float* planes = bufB + N_DEPTH;

    const size_t need = (size_t)(64 + 2 * N_DEPTH + NB * PLANE_IMG) * 4;
    const bool fast = ws_size >= need;

    hipLaunchKernelGGL(init_key_kernel, dim3(1), dim3(1), 0, stream, key);
    hipLaunchKernelGGL(min_kernel, dim3(256), dim3(256), 0, stream, initial, key);

    int nco = N_CV + N_CH;
    hipLaunchKernelGGL(coeff_kernel, dim3((nco + 255) / 256), dim3(256), 0, stream,
                       guide, out_cv, out_ch);
    if (fast) {
        int ntp = NB * PLANE_IMG;
        hipLaunchKernelGGL(prep_planes, dim3((ntp + 255) / 256), dim3(256), 0, stream,
                           out_cv, out_ch, planes);
    }

    float* bufs[2] = {bufA, bufB};
    if (fast) {
        for (int k = 0; k < NSS; ++k) {
            const float* src = (k == 0) ? initial : bufs[(k + 1) & 1];
            float*       dst = (k == NSS - 1) ? out_y : bufs[k & 1];
            if (k == 0)
                hipLaunchKernelGGL((step_t20<true, false>), dim3(256), dim3(NT), 0,
                                   stream, src, dst, planes, key);
            else if (k == NSS - 1)
                hipLaunchKernelGGL((step_t20<false, true>), dim3(256), dim3(NT), 0,
                                   stream, src, dst, planes, key);
            else
                hipLaunchKernelGGL((step_t20<false, false>), dim3(256), dim3(NT), 0,
                                   stream, src, dst, planes, key);
        }
    } else {
        for (int k = 0; k < NSS_F; ++k) {
            const float* src = (k == 0) ? initial : bufs[(k + 1) & 1];
            float*       dst = (k == NSS_F - 1) ? out_y : bufs[k & 1];
            if (k == 0)
                hipLaunchKernelGGL((step_fused<true, false>), dim3(256), dim3(256), 0,
                                   stream, src, dst, out_cv, out_ch, key);
            else if (k == NSS_F - 1)
                hipLaunchKernelGGL((step_fused<false, true>), dim3(256), dim3(256), 0,
                                   stream, src, dst, out_cv, out_ch, key);
            else
                hipLaunchKernelGGL((step_fused<false, false>), dim3(256), dim3(256), 0,
                                   stream, src, dst, out_cv, out_ch, key);
        }
    }
}